// Round 6
// baseline (195.062 us; speedup 1.0000x reference)
//
#include <hip/hip_runtime.h>
#include <math.h>

#define HID 768
#define NB  64
#define HV  384

__device__ __forceinline__ float4 ld4(const float* p) { return *(const float4*)p; }

// ---------------------------------------------------------------------------
// K1: dec (fused dec1p+dec2). One block per t (64 blocks). Exact numeric
// chains of the split version: A0[k] = relu(bs0[k] + fmaf chain b=0..5);
// h2[n] = relu(bs1[n] + sum_{z=0..15 asc} (48-step fmaf partial));
// logits = bs2[n] + plp0+plp1+plp2+plp3 (4x192 contiguous k-partials);
// argmax strict-> ascending n. pred bit-identical to dec1p->dec2.
// Removes H1p (3.1MB write + 3.1MB read) and one launch gap.
// ---------------------------------------------------------------------------
__global__ __launch_bounds__(256)
void dec_kernel(const float* __restrict__ Ws0, const float* __restrict__ bs0,
                const float* __restrict__ Ws1, const float* __restrict__ bs1,
                const float* __restrict__ Ws2, const float* __restrict__ bs2,
                int* __restrict__ pred) {
    __shared__ float A0s[HID];
    __shared__ float h2s[HID];
    __shared__ float plp[4][64];
    const int tid = threadIdx.x;
    const int t = blockIdx.x;

    // A0 = relu(bits@Ws0 + bs0), exact dec1p chain (bias first, b ascending)
    for (int k = tid; k < HID; k += 256) {
        float v = bs0[k];
        #pragma unroll
        for (int b = 0; b < 6; ++b)
            v = fmaf((float)((t >> b) & 1), Ws0[(size_t)b * HID + k], v);
        A0s[k] = fmaxf(v, 0.f);
    }
    __syncthreads();

    // h2[n]: 16 z-chunks of 48, each a 0-init fmaf chain (== dec1p partial),
    // summed ascending onto bs1 (== dec2 phase 1), then relu.
    {
        const int n0 = tid, n1 = tid + 256, n2 = tid + 512;
        float h0 = bs1[n0], h1 = bs1[n1], h2v = bs1[n2];
        for (int z = 0; z < 16; ++z) {
            float p0 = 0.f, p1 = 0.f, p2 = 0.f;
            #pragma unroll 8
            for (int kk = 0; kk < 48; ++kk) {
                const int k = z * 48 + kk;
                const float a = A0s[k];
                const float* wr = Ws1 + (size_t)k * HID;
                p0 = fmaf(a, wr[n0], p0);
                p1 = fmaf(a, wr[n1], p1);
                p2 = fmaf(a, wr[n2], p2);
            }
            h0 += p0; h1 += p1; h2v += p2;
        }
        h2s[n0] = fmaxf(h0, 0.f);
        h2s[n1] = fmaxf(h1, 0.f);
        h2s[n2] = fmaxf(h2v, 0.f);
    }
    __syncthreads();

    // logits partials: 4 parts x 192 contiguous k, exact dec2 phase 2.
    {
        const int n = tid & 63, part = tid >> 6;
        float p = 0.f;
        #pragma unroll 8
        for (int kk = 0; kk < 192; ++kk) {
            const int k = part * 192 + kk;
            p = fmaf(h2s[k], Ws2[k * 64 + n], p);
        }
        plp[part][n] = p;
    }
    __syncthreads();
    if (tid == 0) {
        int best = 0;
        float bv = bs2[0] + plp[0][0] + plp[1][0] + plp[2][0] + plp[3][0];
        for (int n = 1; n < 64; ++n) {
            const float x = bs2[n] + plp[0][n] + plp[1][n] + plp[2][n] + plp[3][n];
            if (x > bv) { bv = x; best = n; }
        }
        pred[t] = best;
    }
}

// ---------------------------------------------------------------------------
// Inline plan prologue (replaces plan_kernel): ballot over pred within wave 0.
// Same logic as the old plan_kernel, ~0.2us per block.
// ---------------------------------------------------------------------------

// K4: gemmA. Proven r0 body (24 n-tiles of 32, 64m x 32n,
// 4x2 frag, BK=64, grid (24, 64, 6)); hdr replaced by in-block plan.
__global__ __launch_bounds__(256)
void gemmA_kernel(const float* __restrict__ Wi0, const float* __restrict__ bi0,
                  const float* __restrict__ Wi1, const int* __restrict__ pred,
                  float* __restrict__ H2p) {
    __shared__ float As[64 * 68];   // [k][m] 17.4 KB
    __shared__ float Bs[64 * 40];   // [k][n] 10.2 KB
    __shared__ int present[64];
    __shared__ int shdr[65];        // [0]=P, [1+rank]=s
    const int tid = threadIdx.x;

    if (tid < 64) present[tid] = 0;
    __syncthreads();
    if (tid < 64) present[pred[tid] & 63] = 1;
    __syncthreads();
    if (tid < 64) {
        const unsigned long long alive = __ballot(present[tid] != 0);
        const int P = __popcll(alive);
        const int rank = __popcll(alive & ((1ull << tid) - 1ull));
        if (tid == 0) shdr[0] = P;
        if (present[tid]) shdr[1 + rank] = tid;
    }
    __syncthreads();

    const int P = shdr[0];
    const int li = blockIdx.y;
    if (li >= P) return;
    const int s = shdr[1 + li];
    const int n0 = blockIdx.x * 32;
    const int z = blockIdx.z;
    const int tx = tid & 15, ty = tid >> 4;
    const float* arow = Wi0 + (size_t)(64 + s) * HID;
    float acc[4][2] = {};

    for (int kt = 0; kt < 2; ++kt) {
        const int k0 = z * 128 + kt * 64;
        #pragma unroll
        for (int pass = 0; pass < 4; ++pass) {
            const int c = pass * 256 + tid;
            const int m = c >> 4, kq = (c & 15) * 4;
            const float4 a1 = ld4(arow + k0 + kq);
            const float4 a2 = ld4(Wi0 + (size_t)m * HID + k0 + kq);
            const float4 bb = ld4(bi0 + k0 + kq);
            As[(kq + 0) * 68 + m] = fmaxf(a1.x + a2.x + bb.x, 0.f);
            As[(kq + 1) * 68 + m] = fmaxf(a1.y + a2.y + bb.y, 0.f);
            As[(kq + 2) * 68 + m] = fmaxf(a1.z + a2.z + bb.z, 0.f);
            As[(kq + 3) * 68 + m] = fmaxf(a1.w + a2.w + bb.w, 0.f);
        }
        #pragma unroll
        for (int pass = 0; pass < 2; ++pass) {
            const int c = pass * 256 + tid;
            const int k = c >> 3, nq = (c & 7) * 4;
            *(float4*)&Bs[k * 40 + nq] = ld4(Wi1 + (size_t)(k0 + k) * HID + n0 + nq);
        }
        __syncthreads();
        #pragma unroll 16
        for (int kk = 0; kk < 64; ++kk) {
            const float4 a4 = *(const float4*)&As[kk * 68 + ty * 4];
            const float2 b2 = *(const float2*)&Bs[kk * 40 + tx * 2];
            const float av[4] = {a4.x, a4.y, a4.z, a4.w};
            #pragma unroll
            for (int a = 0; a < 4; ++a) {
                acc[a][0] = fmaf(av[a], b2.x, acc[a][0]);
                acc[a][1] = fmaf(av[a], b2.y, acc[a][1]);
            }
        }
        __syncthreads();
    }
    float* dst = H2p + ((size_t)(z * 64 + li) * 64) * HID + n0 + tx * 2;
    #pragma unroll
    for (int a = 0; a < 4; ++a)
        *(float2*)(dst + (size_t)(ty * 4 + a) * HID) = make_float2(acc[a][0], acc[a][1]);
}

// ---------------------------------------------------------------------------
// K5: gemmB. r0 body; hdr[0] replaced by in-block plan (P only).
// ---------------------------------------------------------------------------
__global__ __launch_bounds__(256)
void gemmB_kernel(const float* __restrict__ bi1, const float* __restrict__ Wi2,
                  const int* __restrict__ pred, const float* __restrict__ H2p,
                  float* __restrict__ PLf) {
    __shared__ float Ht[64 * 68];   // [n_local][m]
    __shared__ float W2[64 * 68];   // [n_local][o]
    __shared__ int present[64];
    __shared__ int sP;
    const int tid = threadIdx.x;

    if (tid < 64) present[tid] = 0;
    __syncthreads();
    if (tid < 64) present[pred[tid] & 63] = 1;
    __syncthreads();
    if (tid < 64) {
        const unsigned long long alive = __ballot(present[tid] != 0);
        if (tid == 0) sP = __popcll(alive);
    }
    __syncthreads();

    const int P = sP;
    const int li = blockIdx.y;
    if (li >= P) return;
    const int bx = blockIdx.x;      // 0..11
    const int n0 = bx * 64;
    const size_t zstep = (size_t)64 * 64 * HID;

    for (int e = tid; e < 1024; e += 256) {
        const int m = e >> 4, nq = (e & 15) * 4;
        const float* base = H2p + ((size_t)li * 64 + m) * HID + n0 + nq;
        float4 v = ld4(base);
        #pragma unroll
        for (int z = 1; z < 6; ++z) {
            const float4 p = ld4(base + z * zstep);
            v.x += p.x; v.y += p.y; v.z += p.z; v.w += p.w;
        }
        const float4 bb = ld4(bi1 + n0 + nq);
        Ht[(nq + 0) * 68 + m] = fmaxf(v.x + bb.x, 0.f);
        Ht[(nq + 1) * 68 + m] = fmaxf(v.y + bb.y, 0.f);
        Ht[(nq + 2) * 68 + m] = fmaxf(v.z + bb.z, 0.f);
        Ht[(nq + 3) * 68 + m] = fmaxf(v.w + bb.w, 0.f);
    }
    #pragma unroll
    for (int pass = 0; pass < 4; ++pass) {
        const int c = pass * 256 + tid;
        const int cl = c >> 4, oq = (c & 15) * 4;
        *(float4*)&W2[cl * 68 + oq] = ld4(Wi2 + (size_t)(n0 + cl) * 64 + oq);
    }
    __syncthreads();
    const int tx = tid & 15, ty = tid >> 4;
    float pl_[4][4] = {};
    #pragma unroll 16
    for (int kk = 0; kk < 64; ++kk) {
        const float4 a4 = *(const float4*)&Ht[kk * 68 + ty * 4];
        const float4 b4 = *(const float4*)&W2[kk * 68 + tx * 4];
        const float av[4] = {a4.x, a4.y, a4.z, a4.w};
        const float bv[4] = {b4.x, b4.y, b4.z, b4.w};
        #pragma unroll
        for (int a = 0; a < 4; ++a)
            #pragma unroll
            for (int b = 0; b < 4; ++b)
                pl_[a][b] = fmaf(av[a], bv[b], pl_[a][b]);
    }
    #pragma unroll
    for (int a = 0; a < 4; ++a) {
        float4 o = make_float4(pl_[a][0], pl_[a][1], pl_[a][2], pl_[a][3]);
        *(float4*)&PLf[((size_t)(bx * 64 + li) * 64 + ty * 4 + a) * 64 + tx * 4] = o;
    }
}

// ---------------------------------------------------------------------------
// K6: reduceA. r0 body; hdr[65+s] replaced by in-block plan (rank_of_s).
// ---------------------------------------------------------------------------
__global__ __launch_bounds__(256)
void reduceA_kernel(const float* __restrict__ PLf, const float* __restrict__ bi2,
                    const float* __restrict__ Wv0, const float* __restrict__ bv0,
                    const float* __restrict__ Wv1, const float* __restrict__ bv1,
                    const int* __restrict__ pred,
                    int* __restrict__ j_tab, float* __restrict__ sig_tab) {
    __shared__ float lg[16 * 68];
    __shared__ int present[64];
    __shared__ int rank_of[64];
    const int tid = threadIdx.x;
    const int s = blockIdx.x >> 2;

    if (tid < 64) present[tid] = 0;
    __syncthreads();
    if (tid < 64) present[pred[tid] & 63] = 1;
    __syncthreads();
    if (tid < 64) {
        const unsigned long long alive = __ballot(present[tid] != 0);
        const int rank = __popcll(alive & ((1ull << tid) - 1ull));
        rank_of[tid] = present[tid] ? rank : -1;
    }
    __syncthreads();

    const int li = rank_of[s];
    if (li < 0) return;
    const int r0 = blockIdx.x * 16;
    const int rr = tid >> 4, q = tid & 15;
    const int i = (r0 & 63) + rr;
    float4 v = ld4(bi2 + q * 4);
    #pragma unroll
    for (int bx = 0; bx < 12; ++bx) {
        const float4 p = ld4(PLf + ((size_t)(bx * 64 + li) * 64 + i) * 64 + q * 4);
        v.x += p.x; v.y += p.y; v.z += p.z; v.w += p.w;
    }
    *(float4*)&lg[rr * 68 + q * 4] = v;
    __syncthreads();
    if (tid < 16) {
        int best = 0; float bv = lg[tid * 68];
        for (int n = 1; n < 64; ++n) {
            const float x = lg[tid * 68 + n];
            if (x > bv) { bv = x; best = n; }
        }
        j_tab[r0 + tid] = best;
    }
    {
        const int r = r0 + rr;
        const int ii = r & 63;
        const float* w1 = Wv0 + (size_t)(64 + s) * HV;
        const float* w2 = Wv0 + (size_t)ii * HV;
        float sum = 0.f;
        #pragma unroll 4
        for (int c = q; c < HV; c += 16) {
            const float hv = fmaxf(w1[c] + w2[c] + bv0[c], 0.f);
            sum = fmaf(hv, Wv1[c], sum);
        }
        #pragma unroll
        for (int m = 8; m >= 1; m >>= 1) sum += __shfl_xor(sum, m);
        if (q == 0) sig_tab[r] = 1.f / (1.f + expf(-(sum + bv1[0])));
    }
}

// ---------------------------------------------------------------------------
// K7: output. out[b,i] = a_bits[b, j_tab[pred[t_b]*64+i]] * sig_tab[...]
// ---------------------------------------------------------------------------
__global__ __launch_bounds__(256)
void output_kernel(const float* __restrict__ a_bits, const int* __restrict__ shift_amount,
                   const int* __restrict__ pred, const int* __restrict__ j_tab,
                   const float* __restrict__ sig_tab, float* __restrict__ out, int B) {
    const int tid = threadIdx.x;
    const int i = tid & 63;
    const int b = blockIdx.x * 4 + (tid >> 6);
    if (b >= B) return;
    const int t = shift_amount[b] & 63;
    const int s = pred[t];
    const int idx = s * 64 + i;
    const int j = j_tab[idx];
    out[(size_t)b * 64 + i] = a_bits[(size_t)b * 64 + j] * sig_tab[idx];
}

// ---------------------------------------------------------------------------
extern "C" void kernel_launch(void* const* d_in, const int* in_sizes, int n_in,
                              void* d_out, int out_size, void* d_ws, size_t ws_size,
                              hipStream_t stream) {
    const float* a_bits       = (const float*)d_in[0];
    const int*   shift_amount = (const int*)d_in[1];
    const float* Ws0 = (const float*)d_in[2];
    const float* bs0 = (const float*)d_in[3];
    const float* Ws1 = (const float*)d_in[4];
    const float* bs1 = (const float*)d_in[5];
    const float* Ws2 = (const float*)d_in[6];
    const float* bs2 = (const float*)d_in[7];
    const float* Wi0 = (const float*)d_in[8];
    const float* bi0 = (const float*)d_in[9];
    const float* Wi1 = (const float*)d_in[10];
    const float* bi1 = (const float*)d_in[11];
    const float* Wi2 = (const float*)d_in[12];
    const float* bi2 = (const float*)d_in[13];
    const float* Wv0 = (const float*)d_in[14];
    const float* bv0 = (const float*)d_in[15];
    const float* Wv1 = (const float*)d_in[16];
    const float* bv1 = (const float*)d_in[17];
    float* out = (float*)d_out;
    const int B = in_sizes[1];

    char* ws = (char*)d_ws;
    int*   pred    = (int*)ws;                  // 64 ints
    int*   j_tab   = (int*)(ws + 1024);         // 4096 ints
    float* sig_tab = (float*)(ws + 20480);      // 4096 floats
    // H2p (gemmA->gemmB): 6*64*64*768*4 = 75,497,472 B
    float* H2p = (float*)(ws + 65536);
    float* PLf = (float*)(ws + 65536 + 75497472); // 12*64*64*64*4 = 12.6 MB

    dec_kernel<<<64, 256, 0, stream>>>(Ws0, bs0, Ws1, bs1, Ws2, bs2, pred);
    gemmA_kernel<<<dim3(24, 64, 6), 256, 0, stream>>>(Wi0, bi0, Wi1, pred, H2p);
    gemmB_kernel<<<dim3(12, 64), 256, 0, stream>>>(bi1, Wi2, pred, H2p, PLf);
    reduceA_kernel<<<256, 256, 0, stream>>>(PLf, bi2, Wv0, bv0, Wv1, bv1, pred,
                                            j_tab, sig_tab);
    output_kernel<<<(B + 3) / 4, 256, 0, stream>>>(a_bits, shift_amount, pred,
                                                   j_tab, sig_tab, out, B);
}

// Round 7
// 164.388 us; speedup vs baseline: 1.1866x; 1.1866x over previous
//
#include <hip/hip_runtime.h>
#include <math.h>

#define HID 768
#define NB  64
#define HV  384

__device__ __forceinline__ float4 ld4(const float* p) { return *(const float4*)p; }

// ---------------------------------------------------------------------------
// K1: dec1 partial (r0 proven body). H1p[kz][t][n] = sum_{k in chunk kz}
// A0[t][k]*Ws1[k][n], A0 = relu(bits@Ws0+bs0). Grid 192 = 12 n-tiles x 16
// k-chunks of 48. Tiled GEMM keeps all CUs busy (vs 64-matvec fusion that
// measured 70us at 2.6% occupancy in R6).
// ---------------------------------------------------------------------------
__global__ __launch_bounds__(256)
void dec1p_kernel(const float* __restrict__ Ws0, const float* __restrict__ bs0,
                  const float* __restrict__ Ws1, float* __restrict__ H1p) {
    __shared__ float W0s[7 * 48];
    __shared__ float As[48 * 68];
    __shared__ float Bs[48 * 68];
    const int tid = threadIdx.x;
    const int n0 = (blockIdx.x % 12) * 64;
    const int kz = blockIdx.x / 12;
    const int ks = kz * 48;

    for (int e = tid; e < 7 * 48; e += 256) {
        const int r = e / 48, c = e % 48;
        W0s[e] = (r < 6) ? Ws0[(size_t)r * HID + ks + c] : bs0[ks + c];
    }
    for (int e = tid; e < 48 * 16; e += 256) {
        const int k = e >> 4, nq = (e & 15) * 4;
        *(float4*)&Bs[k * 68 + nq] = ld4(Ws1 + (size_t)(ks + k) * HID + n0 + nq);
    }
    __syncthreads();
    for (int e = tid; e < 48 * 64; e += 256) {
        const int k = e >> 6, t = e & 63;
        float v = W0s[6 * 48 + k];
        #pragma unroll
        for (int b = 0; b < 6; ++b)
            v = fmaf((float)((t >> b) & 1), W0s[b * 48 + k], v);
        As[k * 68 + t] = fmaxf(v, 0.f);
    }
    __syncthreads();

    const int tx = tid & 15, ty = tid >> 4;
    float acc[4][4] = {};
    #pragma unroll 8
    for (int kk = 0; kk < 48; ++kk) {
        const float4 a4 = *(const float4*)&As[kk * 68 + ty * 4];
        const float4 b4 = *(const float4*)&Bs[kk * 68 + tx * 4];
        const float av[4] = {a4.x, a4.y, a4.z, a4.w};
        const float bv[4] = {b4.x, b4.y, b4.z, b4.w};
        #pragma unroll
        for (int a = 0; a < 4; ++a)
            #pragma unroll
            for (int b = 0; b < 4; ++b)
                acc[a][b] = fmaf(av[a], bv[b], acc[a][b]);
    }
    #pragma unroll
    for (int a = 0; a < 4; ++a) {
        float4 o = make_float4(acc[a][0], acc[a][1], acc[a][2], acc[a][3]);
        *(float4*)&H1p[((size_t)kz * 64 + ty * 4 + a) * HID + n0 + tx * 4] = o;
    }
}

// ---------------------------------------------------------------------------
// K2: dec2 (R3 proven body). pred[t] = argmax(relu(sum_{z<16} H1p[z][t]+bs1)
// @ Ws2 + bs2). 64 blocks x 1 t-row; z ascending float4 sum, 4x192
// contiguous k-partials summed 0..3, strict-> ascending argmax.
// ---------------------------------------------------------------------------
__global__ __launch_bounds__(256)
void dec2_kernel(const float* __restrict__ H1p, const float* __restrict__ bs1,
                 const float* __restrict__ Ws2, const float* __restrict__ bs2,
                 int* __restrict__ pred) {
    __shared__ float sh[HID];
    __shared__ float plp[4][64];
    const int tid = threadIdx.x;
    const int t = blockIdx.x;

    for (int e = tid; e < HID / 4; e += 256) {
        const int k4 = e * 4;
        float4 v = ld4(bs1 + k4);
        #pragma unroll
        for (int z = 0; z < 16; ++z) {
            const float4 p = ld4(H1p + ((size_t)z * 64 + t) * HID + k4);
            v.x += p.x; v.y += p.y; v.z += p.z; v.w += p.w;
        }
        sh[k4 + 0] = fmaxf(v.x, 0.f);
        sh[k4 + 1] = fmaxf(v.y, 0.f);
        sh[k4 + 2] = fmaxf(v.z, 0.f);
        sh[k4 + 3] = fmaxf(v.w, 0.f);
    }
    __syncthreads();
    {
        const int n = tid & 63, part = tid >> 6;
        float p = 0.f;
        #pragma unroll 8
        for (int kk = 0; kk < 192; ++kk) {
            const int k = part * 192 + kk;
            p = fmaf(sh[k], Ws2[k * 64 + n], p);
        }
        plp[part][n] = p;
    }
    __syncthreads();
    if (tid == 0) {
        int best = 0;
        float bv = bs2[0] + plp[0][0] + plp[1][0] + plp[2][0] + plp[3][0];
        for (int n = 1; n < 64; ++n) {
            const float x = bs2[n] + plp[0][n] + plp[1][n] + plp[2][n] + plp[3][n];
            if (x > bv) { bv = x; best = n; }
        }
        pred[t] = best;
    }
}

// ---------------------------------------------------------------------------
// K4: gemmA. Proven r0 body (24 n-tiles of 32, 64m x 32n, 4x2 frag, BK=64,
// grid (24, 64, 6)); plan ballot inlined (replaces plan_kernel).
// ---------------------------------------------------------------------------
__global__ __launch_bounds__(256)
void gemmA_kernel(const float* __restrict__ Wi0, const float* __restrict__ bi0,
                  const float* __restrict__ Wi1, const int* __restrict__ pred,
                  float* __restrict__ H2p) {
    __shared__ float As[64 * 68];   // [k][m] 17.4 KB
    __shared__ float Bs[64 * 40];   // [k][n] 10.2 KB
    __shared__ int present[64];
    __shared__ int shdr[65];        // [0]=P, [1+rank]=s
    const int tid = threadIdx.x;

    if (tid < 64) present[tid] = 0;
    __syncthreads();
    if (tid < 64) present[pred[tid] & 63] = 1;
    __syncthreads();
    if (tid < 64) {
        const unsigned long long alive = __ballot(present[tid] != 0);
        const int P = __popcll(alive);
        const int rank = __popcll(alive & ((1ull << tid) - 1ull));
        if (tid == 0) shdr[0] = P;
        if (present[tid]) shdr[1 + rank] = tid;
    }
    __syncthreads();

    const int P = shdr[0];
    const int li = blockIdx.y;
    if (li >= P) return;
    const int s = shdr[1 + li];
    const int n0 = blockIdx.x * 32;
    const int z = blockIdx.z;
    const int tx = tid & 15, ty = tid >> 4;
    const float* arow = Wi0 + (size_t)(64 + s) * HID;
    float acc[4][2] = {};

    for (int kt = 0; kt < 2; ++kt) {
        const int k0 = z * 128 + kt * 64;
        #pragma unroll
        for (int pass = 0; pass < 4; ++pass) {
            const int c = pass * 256 + tid;
            const int m = c >> 4, kq = (c & 15) * 4;
            const float4 a1 = ld4(arow + k0 + kq);
            const float4 a2 = ld4(Wi0 + (size_t)m * HID + k0 + kq);
            const float4 bb = ld4(bi0 + k0 + kq);
            As[(kq + 0) * 68 + m] = fmaxf(a1.x + a2.x + bb.x, 0.f);
            As[(kq + 1) * 68 + m] = fmaxf(a1.y + a2.y + bb.y, 0.f);
            As[(kq + 2) * 68 + m] = fmaxf(a1.z + a2.z + bb.z, 0.f);
            As[(kq + 3) * 68 + m] = fmaxf(a1.w + a2.w + bb.w, 0.f);
        }
        #pragma unroll
        for (int pass = 0; pass < 2; ++pass) {
            const int c = pass * 256 + tid;
            const int k = c >> 3, nq = (c & 7) * 4;
            *(float4*)&Bs[k * 40 + nq] = ld4(Wi1 + (size_t)(k0 + k) * HID + n0 + nq);
        }
        __syncthreads();
        #pragma unroll 16
        for (int kk = 0; kk < 64; ++kk) {
            const float4 a4 = *(const float4*)&As[kk * 68 + ty * 4];
            const float2 b2 = *(const float2*)&Bs[kk * 40 + tx * 2];
            const float av[4] = {a4.x, a4.y, a4.z, a4.w};
            #pragma unroll
            for (int a = 0; a < 4; ++a) {
                acc[a][0] = fmaf(av[a], b2.x, acc[a][0]);
                acc[a][1] = fmaf(av[a], b2.y, acc[a][1]);
            }
        }
        __syncthreads();
    }
    float* dst = H2p + ((size_t)(z * 64 + li) * 64) * HID + n0 + tx * 2;
    #pragma unroll
    for (int a = 0; a < 4; ++a)
        *(float2*)(dst + (size_t)(ty * 4 + a) * HID) = make_float2(acc[a][0], acc[a][1]);
}

// ---------------------------------------------------------------------------
// K5: gemmB. r0 body; plan ballot inlined (P only).
// ---------------------------------------------------------------------------
__global__ __launch_bounds__(256)
void gemmB_kernel(const float* __restrict__ bi1, const float* __restrict__ Wi2,
                  const int* __restrict__ pred, const float* __restrict__ H2p,
                  float* __restrict__ PLf) {
    __shared__ float Ht[64 * 68];   // [n_local][m]
    __shared__ float W2[64 * 68];   // [n_local][o]
    __shared__ int present[64];
    __shared__ int sP;
    const int tid = threadIdx.x;

    if (tid < 64) present[tid] = 0;
    __syncthreads();
    if (tid < 64) present[pred[tid] & 63] = 1;
    __syncthreads();
    if (tid < 64) {
        const unsigned long long alive = __ballot(present[tid] != 0);
        if (tid == 0) sP = __popcll(alive);
    }
    __syncthreads();

    const int P = sP;
    const int li = blockIdx.y;
    if (li >= P) return;
    const int bx = blockIdx.x;      // 0..11
    const int n0 = bx * 64;
    const size_t zstep = (size_t)64 * 64 * HID;

    for (int e = tid; e < 1024; e += 256) {
        const int m = e >> 4, nq = (e & 15) * 4;
        const float* base = H2p + ((size_t)li * 64 + m) * HID + n0 + nq;
        float4 v = ld4(base);
        #pragma unroll
        for (int z = 1; z < 6; ++z) {
            const float4 p = ld4(base + z * zstep);
            v.x += p.x; v.y += p.y; v.z += p.z; v.w += p.w;
        }
        const float4 bb = ld4(bi1 + n0 + nq);
        Ht[(nq + 0) * 68 + m] = fmaxf(v.x + bb.x, 0.f);
        Ht[(nq + 1) * 68 + m] = fmaxf(v.y + bb.y, 0.f);
        Ht[(nq + 2) * 68 + m] = fmaxf(v.z + bb.z, 0.f);
        Ht[(nq + 3) * 68 + m] = fmaxf(v.w + bb.w, 0.f);
    }
    #pragma unroll
    for (int pass = 0; pass < 4; ++pass) {
        const int c = pass * 256 + tid;
        const int cl = c >> 4, oq = (c & 15) * 4;
        *(float4*)&W2[cl * 68 + oq] = ld4(Wi2 + (size_t)(n0 + cl) * 64 + oq);
    }
    __syncthreads();
    const int tx = tid & 15, ty = tid >> 4;
    float pl_[4][4] = {};
    #pragma unroll 16
    for (int kk = 0; kk < 64; ++kk) {
        const float4 a4 = *(const float4*)&Ht[kk * 68 + ty * 4];
        const float4 b4 = *(const float4*)&W2[kk * 68 + tx * 4];
        const float av[4] = {a4.x, a4.y, a4.z, a4.w};
        const float bv[4] = {b4.x, b4.y, b4.z, b4.w};
        #pragma unroll
        for (int a = 0; a < 4; ++a)
            #pragma unroll
            for (int b = 0; b < 4; ++b)
                pl_[a][b] = fmaf(av[a], bv[b], pl_[a][b]);
    }
    #pragma unroll
    for (int a = 0; a < 4; ++a) {
        float4 o = make_float4(pl_[a][0], pl_[a][1], pl_[a][2], pl_[a][3]);
        *(float4*)&PLf[((size_t)(bx * 64 + li) * 64 + ty * 4 + a) * 64 + tx * 4] = o;
    }
}

// ---------------------------------------------------------------------------
// K6: reduceA. r0 body; plan ballot inlined (rank_of_s).
// ---------------------------------------------------------------------------
__global__ __launch_bounds__(256)
void reduceA_kernel(const float* __restrict__ PLf, const float* __restrict__ bi2,
                    const float* __restrict__ Wv0, const float* __restrict__ bv0,
                    const float* __restrict__ Wv1, const float* __restrict__ bv1,
                    const int* __restrict__ pred,
                    int* __restrict__ j_tab, float* __restrict__ sig_tab) {
    __shared__ float lg[16 * 68];
    __shared__ int present[64];
    __shared__ int rank_of[64];
    const int tid = threadIdx.x;
    const int s = blockIdx.x >> 2;

    if (tid < 64) present[tid] = 0;
    __syncthreads();
    if (tid < 64) present[pred[tid] & 63] = 1;
    __syncthreads();
    if (tid < 64) {
        const unsigned long long alive = __ballot(present[tid] != 0);
        const int rank = __popcll(alive & ((1ull << tid) - 1ull));
        rank_of[tid] = present[tid] ? rank : -1;
    }
    __syncthreads();

    const int li = rank_of[s];
    if (li < 0) return;
    const int r0 = blockIdx.x * 16;
    const int rr = tid >> 4, q = tid & 15;
    const int i = (r0 & 63) + rr;
    float4 v = ld4(bi2 + q * 4);
    #pragma unroll
    for (int bx = 0; bx < 12; ++bx) {
        const float4 p = ld4(PLf + ((size_t)(bx * 64 + li) * 64 + i) * 64 + q * 4);
        v.x += p.x; v.y += p.y; v.z += p.z; v.w += p.w;
    }
    *(float4*)&lg[rr * 68 + q * 4] = v;
    __syncthreads();
    if (tid < 16) {
        int best = 0; float bv = lg[tid * 68];
        for (int n = 1; n < 64; ++n) {
            const float x = lg[tid * 68 + n];
            if (x > bv) { bv = x; best = n; }
        }
        j_tab[r0 + tid] = best;
    }
    {
        const int r = r0 + rr;
        const int ii = r & 63;
        const float* w1 = Wv0 + (size_t)(64 + s) * HV;
        const float* w2 = Wv0 + (size_t)ii * HV;
        float sum = 0.f;
        #pragma unroll 4
        for (int c = q; c < HV; c += 16) {
            const float hv = fmaxf(w1[c] + w2[c] + bv0[c], 0.f);
            sum = fmaf(hv, Wv1[c], sum);
        }
        #pragma unroll
        for (int m = 8; m >= 1; m >>= 1) sum += __shfl_xor(sum, m);
        if (q == 0) sig_tab[r] = 1.f / (1.f + expf(-(sum + bv1[0])));
    }
}

// ---------------------------------------------------------------------------
// K7: output. out[b,i] = a_bits[b, j_tab[pred[t_b]*64+i]] * sig_tab[...]
// ---------------------------------------------------------------------------
__global__ __launch_bounds__(256)
void output_kernel(const float* __restrict__ a_bits, const int* __restrict__ shift_amount,
                   const int* __restrict__ pred, const int* __restrict__ j_tab,
                   const float* __restrict__ sig_tab, float* __restrict__ out, int B) {
    const int tid = threadIdx.x;
    const int i = tid & 63;
    const int b = blockIdx.x * 4 + (tid >> 6);
    if (b >= B) return;
    const int t = shift_amount[b] & 63;
    const int s = pred[t];
    const int idx = s * 64 + i;
    const int j = j_tab[idx];
    out[(size_t)b * 64 + i] = a_bits[(size_t)b * 64 + j] * sig_tab[idx];
}

// ---------------------------------------------------------------------------
extern "C" void kernel_launch(void* const* d_in, const int* in_sizes, int n_in,
                              void* d_out, int out_size, void* d_ws, size_t ws_size,
                              hipStream_t stream) {
    const float* a_bits       = (const float*)d_in[0];
    const int*   shift_amount = (const int*)d_in[1];
    const float* Ws0 = (const float*)d_in[2];
    const float* bs0 = (const float*)d_in[3];
    const float* Ws1 = (const float*)d_in[4];
    const float* bs1 = (const float*)d_in[5];
    const float* Ws2 = (const float*)d_in[6];
    const float* bs2 = (const float*)d_in[7];
    const float* Wi0 = (const float*)d_in[8];
    const float* bi0 = (const float*)d_in[9];
    const float* Wi1 = (const float*)d_in[10];
    const float* bi1 = (const float*)d_in[11];
    const float* Wi2 = (const float*)d_in[12];
    const float* bi2 = (const float*)d_in[13];
    const float* Wv0 = (const float*)d_in[14];
    const float* bv0 = (const float*)d_in[15];
    const float* Wv1 = (const float*)d_in[16];
    const float* bv1 = (const float*)d_in[17];
    float* out = (float*)d_out;
    const int B = in_sizes[1];

    char* ws = (char*)d_ws;
    int*   pred    = (int*)ws;                  // 64 ints
    int*   j_tab   = (int*)(ws + 1024);         // 4096 ints
    float* sig_tab = (float*)(ws + 20480);      // 4096 floats
    // Aliased region at +65536 (stream-ordered reuse):
    //   H1p (dec1p->dec2): 16*64*768*4 = 3.1 MB
    //   H2p (gemmA->gemmB): 6*64*64*768*4 = 75,497,472 B
    float* H1p = (float*)(ws + 65536);
    float* H2p = (float*)(ws + 65536);
    float* PLf = (float*)(ws + 65536 + 75497472); // 12*64*64*64*4 = 12.6 MB

    dec1p_kernel<<<192, 256, 0, stream>>>(Ws0, bs0, Ws1, H1p);
    dec2_kernel<<<64, 256, 0, stream>>>(H1p, bs1, Ws2, bs2, pred);
    gemmA_kernel<<<dim3(24, 64, 6), 256, 0, stream>>>(Wi0, bi0, Wi1, pred, H2p);
    gemmB_kernel<<<dim3(12, 64), 256, 0, stream>>>(bi1, Wi2, pred, H2p, PLf);
    reduceA_kernel<<<256, 256, 0, stream>>>(PLf, bi2, Wv0, bv0, Wv1, bv1, pred,
                                            j_tab, sig_tab);
    output_kernel<<<(B + 3) / 4, 256, 0, stream>>>(a_bits, shift_amount, pred,
                                                   j_tab, sig_tab, out, B);
}

// Round 8
// 154.797 us; speedup vs baseline: 1.2601x; 1.0620x over previous
//
#include <hip/hip_runtime.h>
#include <math.h>

#define HID 768
#define NB  64
#define HV  384

__device__ __forceinline__ float4 ld4(const float* p) { return *(const float4*)p; }

// ---------------------------------------------------------------------------
// K1: dec1 partial (r0 proven body). H1p[kz][t][n] = sum_{k in chunk kz}
// A0[t][k]*Ws1[k][n], A0 = relu(bits@Ws0+bs0). Grid 192 = 12 n-tiles x 16
// k-chunks of 48.
// ---------------------------------------------------------------------------
__global__ __launch_bounds__(256)
void dec1p_kernel(const float* __restrict__ Ws0, const float* __restrict__ bs0,
                  const float* __restrict__ Ws1, float* __restrict__ H1p) {
    __shared__ float W0s[7 * 48];
    __shared__ float As[48 * 68];
    __shared__ float Bs[48 * 68];
    const int tid = threadIdx.x;
    const int n0 = (blockIdx.x % 12) * 64;
    const int kz = blockIdx.x / 12;
    const int ks = kz * 48;

    for (int e = tid; e < 7 * 48; e += 256) {
        const int r = e / 48, c = e % 48;
        W0s[e] = (r < 6) ? Ws0[(size_t)r * HID + ks + c] : bs0[ks + c];
    }
    for (int e = tid; e < 48 * 16; e += 256) {
        const int k = e >> 4, nq = (e & 15) * 4;
        *(float4*)&Bs[k * 68 + nq] = ld4(Ws1 + (size_t)(ks + k) * HID + n0 + nq);
    }
    __syncthreads();
    for (int e = tid; e < 48 * 64; e += 256) {
        const int k = e >> 6, t = e & 63;
        float v = W0s[6 * 48 + k];
        #pragma unroll
        for (int b = 0; b < 6; ++b)
            v = fmaf((float)((t >> b) & 1), W0s[b * 48 + k], v);
        As[k * 68 + t] = fmaxf(v, 0.f);
    }
    __syncthreads();

    const int tx = tid & 15, ty = tid >> 4;
    float acc[4][4] = {};
    #pragma unroll 8
    for (int kk = 0; kk < 48; ++kk) {
        const float4 a4 = *(const float4*)&As[kk * 68 + ty * 4];
        const float4 b4 = *(const float4*)&Bs[kk * 68 + tx * 4];
        const float av[4] = {a4.x, a4.y, a4.z, a4.w};
        const float bv[4] = {b4.x, b4.y, b4.z, b4.w};
        #pragma unroll
        for (int a = 0; a < 4; ++a)
            #pragma unroll
            for (int b = 0; b < 4; ++b)
                acc[a][b] = fmaf(av[a], bv[b], acc[a][b]);
    }
    #pragma unroll
    for (int a = 0; a < 4; ++a) {
        float4 o = make_float4(acc[a][0], acc[a][1], acc[a][2], acc[a][3]);
        *(float4*)&H1p[((size_t)kz * 64 + ty * 4 + a) * HID + n0 + tx * 4] = o;
    }
}

// ---------------------------------------------------------------------------
// K2: dec2 (measured-good body, R3/R7). pred[t] = argmax(relu(sum_{z<16}
// H1p[z][t]+bs1) @ Ws2 + bs2). 64 blocks x 1 t-row; z ascending float4 sum,
// 4x192 contiguous k-partials summed 0..3, strict-> ascending argmax.
// ---------------------------------------------------------------------------
__global__ __launch_bounds__(256)
void dec2_kernel(const float* __restrict__ H1p, const float* __restrict__ bs1,
                 const float* __restrict__ Ws2, const float* __restrict__ bs2,
                 int* __restrict__ pred) {
    __shared__ float sh[HID];
    __shared__ float plp[4][64];
    const int tid = threadIdx.x;
    const int t = blockIdx.x;

    for (int e = tid; e < HID / 4; e += 256) {
        const int k4 = e * 4;
        float4 v = ld4(bs1 + k4);
        #pragma unroll
        for (int z = 0; z < 16; ++z) {
            const float4 p = ld4(H1p + ((size_t)z * 64 + t) * HID + k4);
            v.x += p.x; v.y += p.y; v.z += p.z; v.w += p.w;
        }
        sh[k4 + 0] = fmaxf(v.x, 0.f);
        sh[k4 + 1] = fmaxf(v.y, 0.f);
        sh[k4 + 2] = fmaxf(v.z, 0.f);
        sh[k4 + 3] = fmaxf(v.w, 0.f);
    }
    __syncthreads();
    {
        const int n = tid & 63, part = tid >> 6;
        float p = 0.f;
        #pragma unroll 8
        for (int kk = 0; kk < 192; ++kk) {
            const int k = part * 192 + kk;
            p = fmaf(sh[k], Ws2[k * 64 + n], p);
        }
        plp[part][n] = p;
    }
    __syncthreads();
    if (tid == 0) {
        int best = 0;
        float bv = bs2[0] + plp[0][0] + plp[1][0] + plp[2][0] + plp[3][0];
        for (int n = 1; n < 64; ++n) {
            const float x = bs2[n] + plp[0][n] + plp[1][n] + plp[2][n] + plp[3][n];
            if (x > bv) { bv = x; best = n; }
        }
        pred[t] = best;
    }
}

// ---------------------------------------------------------------------------
// K3: plan (r0 proven body, RESTORED — inlined ballots cost ~5us across 10k
// blocks in R7). hdr[0]=P; hdr[1+rank]=s_of_rank; hdr[65+s]=rank_of_s (-1).
// ---------------------------------------------------------------------------
__global__ __launch_bounds__(64)
void plan_kernel(const int* __restrict__ pred, int* __restrict__ hdr) {
    const int lane = threadIdx.x;
    __shared__ int present[64];
    present[lane] = 0;
    __syncthreads();
    present[pred[lane] & 63] = 1;
    __syncthreads();
    const unsigned long long alive = __ballot(present[lane] != 0);
    const int P = __popcll(alive);
    const int rank = __popcll(alive & ((1ull << lane) - 1ull));
    if (lane == 0) hdr[0] = P;
    if (present[lane]) { hdr[1 + rank] = lane; hdr[65 + lane] = rank; }
    else hdr[65 + lane] = -1;
}

// ---------------------------------------------------------------------------
// K4: gemmA. EXPERIMENT: 64m x 64n tile, 4x4 frag (dec1p's proven inner
// structure), BK=64, grid (12 n-tiles, 64 rank slots, 6 z). LDS bytes/FMA
// drops 3.0 -> 2.0 (32B per 16 fma vs 24B per 8). Live blocks 12*P*6 ~ 2952
// (11.5/CU, 4 resident at 35KB LDS) -- keeps the TLP that R1's 3-tile
// version lost. Per-output k-chain still ascending within the 128-k z-chunk
// (frag shape doesn't change product order) -> H2p bit-identical.
// ---------------------------------------------------------------------------
__global__ __launch_bounds__(256)
void gemmA_kernel(const float* __restrict__ Wi0, const float* __restrict__ bi0,
                  const float* __restrict__ Wi1, const int* __restrict__ hdr,
                  float* __restrict__ H2p) {
    __shared__ float As[64 * 68];   // [k][m] 17.4 KB
    __shared__ float Bs[64 * 68];   // [k][n] 17.4 KB
    const int tid = threadIdx.x;
    const int P = hdr[0];
    const int li = blockIdx.y;
    if (li >= P) return;
    const int s = hdr[1 + li];
    const int n0 = blockIdx.x * 64;
    const int z = blockIdx.z;
    const int tx = tid & 15, ty = tid >> 4;
    const float* arow = Wi0 + (size_t)(64 + s) * HID;
    float acc[4][4] = {};

    for (int kt = 0; kt < 2; ++kt) {
        const int k0 = z * 128 + kt * 64;
        #pragma unroll
        for (int pass = 0; pass < 4; ++pass) {
            const int c = pass * 256 + tid;
            const int m = c >> 4, kq = (c & 15) * 4;
            const float4 a1 = ld4(arow + k0 + kq);
            const float4 a2 = ld4(Wi0 + (size_t)m * HID + k0 + kq);
            const float4 bb = ld4(bi0 + k0 + kq);
            As[(kq + 0) * 68 + m] = fmaxf(a1.x + a2.x + bb.x, 0.f);
            As[(kq + 1) * 68 + m] = fmaxf(a1.y + a2.y + bb.y, 0.f);
            As[(kq + 2) * 68 + m] = fmaxf(a1.z + a2.z + bb.z, 0.f);
            As[(kq + 3) * 68 + m] = fmaxf(a1.w + a2.w + bb.w, 0.f);
        }
        #pragma unroll
        for (int pass = 0; pass < 4; ++pass) {
            const int c = pass * 256 + tid;
            const int k = c >> 4, nq = (c & 15) * 4;
            *(float4*)&Bs[k * 68 + nq] = ld4(Wi1 + (size_t)(k0 + k) * HID + n0 + nq);
        }
        __syncthreads();
        #pragma unroll 8
        for (int kk = 0; kk < 64; ++kk) {
            const float4 a4 = *(const float4*)&As[kk * 68 + ty * 4];
            const float4 b4 = *(const float4*)&Bs[kk * 68 + tx * 4];
            const float av[4] = {a4.x, a4.y, a4.z, a4.w};
            const float bv[4] = {b4.x, b4.y, b4.z, b4.w};
            #pragma unroll
            for (int a = 0; a < 4; ++a)
                #pragma unroll
                for (int b = 0; b < 4; ++b)
                    acc[a][b] = fmaf(av[a], bv[b], acc[a][b]);
        }
        __syncthreads();
    }
    float* dst = H2p + ((size_t)(z * 64 + li) * 64) * HID + n0;
    #pragma unroll
    for (int a = 0; a < 4; ++a) {
        float4 o = make_float4(acc[a][0], acc[a][1], acc[a][2], acc[a][3]);
        *(float4*)(dst + (size_t)(ty * 4 + a) * HID + tx * 4) = o;
    }
}

// ---------------------------------------------------------------------------
// K5: gemmB (r0 proven body, hdr). Grid (12 n-slices of 64, 64 rank slots).
// h2 = relu(sum_{z<6 ascending} + bi1); partial logits vs Wi2 slice -> PLf.
// ---------------------------------------------------------------------------
__global__ __launch_bounds__(256)
void gemmB_kernel(const float* __restrict__ bi1, const float* __restrict__ Wi2,
                  const int* __restrict__ hdr, const float* __restrict__ H2p,
                  float* __restrict__ PLf) {
    __shared__ float Ht[64 * 68];   // [n_local][m]
    __shared__ float W2[64 * 68];   // [n_local][o]
    const int tid = threadIdx.x;
    const int P = hdr[0];
    const int li = blockIdx.y;
    if (li >= P) return;
    const int bx = blockIdx.x;      // 0..11
    const int n0 = bx * 64;
    const size_t zstep = (size_t)64 * 64 * HID;

    for (int e = tid; e < 1024; e += 256) {
        const int m = e >> 4, nq = (e & 15) * 4;
        const float* base = H2p + ((size_t)li * 64 + m) * HID + n0 + nq;
        float4 v = ld4(base);
        #pragma unroll
        for (int z = 1; z < 6; ++z) {
            const float4 p = ld4(base + z * zstep);
            v.x += p.x; v.y += p.y; v.z += p.z; v.w += p.w;
        }
        const float4 bb = ld4(bi1 + n0 + nq);
        Ht[(nq + 0) * 68 + m] = fmaxf(v.x + bb.x, 0.f);
        Ht[(nq + 1) * 68 + m] = fmaxf(v.y + bb.y, 0.f);
        Ht[(nq + 2) * 68 + m] = fmaxf(v.z + bb.z, 0.f);
        Ht[(nq + 3) * 68 + m] = fmaxf(v.w + bb.w, 0.f);
    }
    #pragma unroll
    for (int pass = 0; pass < 4; ++pass) {
        const int c = pass * 256 + tid;
        const int cl = c >> 4, oq = (c & 15) * 4;
        *(float4*)&W2[cl * 68 + oq] = ld4(Wi2 + (size_t)(n0 + cl) * 64 + oq);
    }
    __syncthreads();
    const int tx = tid & 15, ty = tid >> 4;
    float pl_[4][4] = {};
    #pragma unroll 16
    for (int kk = 0; kk < 64; ++kk) {
        const float4 a4 = *(const float4*)&Ht[kk * 68 + ty * 4];
        const float4 b4 = *(const float4*)&W2[kk * 68 + tx * 4];
        const float av[4] = {a4.x, a4.y, a4.z, a4.w};
        const float bv[4] = {b4.x, b4.y, b4.z, b4.w};
        #pragma unroll
        for (int a = 0; a < 4; ++a)
            #pragma unroll
            for (int b = 0; b < 4; ++b)
                pl_[a][b] = fmaf(av[a], bv[b], pl_[a][b]);
    }
    #pragma unroll
    for (int a = 0; a < 4; ++a) {
        float4 o = make_float4(pl_[a][0], pl_[a][1], pl_[a][2], pl_[a][3]);
        *(float4*)&PLf[((size_t)(bx * 64 + li) * 64 + ty * 4 + a) * 64 + tx * 4] = o;
    }
}

// ---------------------------------------------------------------------------
// K6: reduceA (r0 proven body, hdr). logits = bi2 + sum_{bx<12} PLf[bx][li]
// -> argmax -> j_tab; validity sigmoid. Grid 256; dead s exits.
// ---------------------------------------------------------------------------
__global__ __launch_bounds__(256)
void reduceA_kernel(const float* __restrict__ PLf, const float* __restrict__ bi2,
                    const float* __restrict__ Wv0, const float* __restrict__ bv0,
                    const float* __restrict__ Wv1, const float* __restrict__ bv1,
                    const int* __restrict__ hdr,
                    int* __restrict__ j_tab, float* __restrict__ sig_tab) {
    __shared__ float lg[16 * 68];
    const int tid = threadIdx.x;
    const int s = blockIdx.x >> 2;
    const int li = hdr[65 + s];
    if (li < 0) return;
    const int r0 = blockIdx.x * 16;
    const int rr = tid >> 4, q = tid & 15;
    const int i = (r0 & 63) + rr;
    float4 v = ld4(bi2 + q * 4);
    #pragma unroll
    for (int bx = 0; bx < 12; ++bx) {
        const float4 p = ld4(PLf + ((size_t)(bx * 64 + li) * 64 + i) * 64 + q * 4);
        v.x += p.x; v.y += p.y; v.z += p.z; v.w += p.w;
    }
    *(float4*)&lg[rr * 68 + q * 4] = v;
    __syncthreads();
    if (tid < 16) {
        int best = 0; float bv = lg[tid * 68];
        for (int n = 1; n < 64; ++n) {
            const float x = lg[tid * 68 + n];
            if (x > bv) { bv = x; best = n; }
        }
        j_tab[r0 + tid] = best;
    }
    {
        const int r = r0 + rr;
        const int ii = r & 63;
        const float* w1 = Wv0 + (size_t)(64 + s) * HV;
        const float* w2 = Wv0 + (size_t)ii * HV;
        float sum = 0.f;
        #pragma unroll 4
        for (int c = q; c < HV; c += 16) {
            const float hv = fmaxf(w1[c] + w2[c] + bv0[c], 0.f);
            sum = fmaf(hv, Wv1[c], sum);
        }
        #pragma unroll
        for (int m = 8; m >= 1; m >>= 1) sum += __shfl_xor(sum, m);
        if (q == 0) sig_tab[r] = 1.f / (1.f + expf(-(sum + bv1[0])));
    }
}

// ---------------------------------------------------------------------------
// K7: output. out[b,i] = a_bits[b, j_tab[pred[t_b]*64+i]] * sig_tab[...]
// ---------------------------------------------------------------------------
__global__ __launch_bounds__(256)
void output_kernel(const float* __restrict__ a_bits, const int* __restrict__ shift_amount,
                   const int* __restrict__ pred, const int* __restrict__ j_tab,
                   const float* __restrict__ sig_tab, float* __restrict__ out, int B) {
    const int tid = threadIdx.x;
    const int i = tid & 63;
    const int b = blockIdx.x * 4 + (tid >> 6);
    if (b >= B) return;
    const int t = shift_amount[b] & 63;
    const int s = pred[t];
    const int idx = s * 64 + i;
    const int j = j_tab[idx];
    out[(size_t)b * 64 + i] = a_bits[(size_t)b * 64 + j] * sig_tab[idx];
}

// ---------------------------------------------------------------------------
extern "C" void kernel_launch(void* const* d_in, const int* in_sizes, int n_in,
                              void* d_out, int out_size, void* d_ws, size_t ws_size,
                              hipStream_t stream) {
    const float* a_bits       = (const float*)d_in[0];
    const int*   shift_amount = (const int*)d_in[1];
    const float* Ws0 = (const float*)d_in[2];
    const float* bs0 = (const float*)d_in[3];
    const float* Ws1 = (const float*)d_in[4];
    const float* bs1 = (const float*)d_in[5];
    const float* Ws2 = (const float*)d_in[6];
    const float* bs2 = (const float*)d_in[7];
    const float* Wi0 = (const float*)d_in[8];
    const float* bi0 = (const float*)d_in[9];
    const float* Wi1 = (const float*)d_in[10];
    const float* bi1 = (const float*)d_in[11];
    const float* Wi2 = (const float*)d_in[12];
    const float* bi2 = (const float*)d_in[13];
    const float* Wv0 = (const float*)d_in[14];
    const float* bv0 = (const float*)d_in[15];
    const float* Wv1 = (const float*)d_in[16];
    const float* bv1 = (const float*)d_in[17];
    float* out = (float*)d_out;
    const int B = in_sizes[1];

    char* ws = (char*)d_ws;
    int*   pred    = (int*)ws;                  // 64 ints
    int*   j_tab   = (int*)(ws + 1024);         // 4096 ints
    float* sig_tab = (float*)(ws + 20480);      // 4096 floats
    int*   hdr     = (int*)(ws + 40960);        // P + s_of_rank[64] + rank_of_s[64]
    // Aliased region at +65536 (stream-ordered reuse):
    //   H1p (dec1p->dec2): 16*64*768*4 = 3.1 MB
    //   H2p (gemmA->gemmB): 6*64*64*768*4 = 75,497,472 B
    float* H1p = (float*)(ws + 65536);
    float* H2p = (float*)(ws + 65536);
    float* PLf = (float*)(ws + 65536 + 75497472); // 12*64*64*64*4 = 12.6 MB

    dec1p_kernel<<<192, 256, 0, stream>>>(Ws0, bs0, Ws1, H1p);
    dec2_kernel<<<64, 256, 0, stream>>>(H1p, bs1, Ws2, bs2, pred);
    plan_kernel<<<1, 64, 0, stream>>>(pred, hdr);
    gemmA_kernel<<<dim3(12, 64, 6), 256, 0, stream>>>(Wi0, bi0, Wi1, hdr, H2p);
    gemmB_kernel<<<dim3(12, 64), 256, 0, stream>>>(bi1, Wi2, hdr, H2p, PLf);
    reduceA_kernel<<<256, 256, 0, stream>>>(PLf, bi2, Wv0, bv0, Wv1, bv1, hdr,
                                            j_tab, sig_tab);
    output_kernel<<<(B + 3) / 4, 256, 0, stream>>>(a_bits, shift_amount, pred,
                                                   j_tab, sig_tab, out, B);
}